// Round 2
// baseline (79.306 us; speedup 1.0000x reference)
//
#include <hip/hip_runtime.h>
#include <math.h>

#define NG 1024
#define HH 256
#define WW 256
#define TILE_PX 64
#define WT 4
#define FOCAL_F 256.0f      // W / (2 * TAN_FOV)
#define RADII_MULT_F 5.0f
#define SEG 256

// ws layout, in float4 units:
//   [0,    NG)  rect : (rminx, rmaxx, rminy, rmaxy)
//   [NG,  2NG)  attrA: (m2x, m2y, kexp, op)
//   [2NG, 3NG)  attrB: (r, g, b, dep)
// All indexed by depth rank (stable argsort of view-space z).

__global__ __launch_bounds__(256) void prep_rank_kernel(
    const float* __restrict__ means3d, const float* __restrict__ opacity,
    const float* __restrict__ scale3d, const float* __restrict__ features,
    const float* __restrict__ viewm, const float* __restrict__ projm,
    float* __restrict__ ws)
{
    __shared__ float s_dep[NG];
    __shared__ int s_rank[64][4];

    const int t = threadIdx.x;
    const int l = t & 63;        // lane / gaussian slot within block
    const int q = t >> 6;        // wave = quarter of the j-range
    const int gid = blockIdx.x * 64 + l;

    // depths for all 1024 gaussians (256 threads x 4)
    const float v2 = viewm[2], v6 = viewm[6], v10 = viewm[10], v14 = viewm[14];
#pragma unroll
    for (int c = 0; c < NG / 256; c++) {
        const int g = c * 256 + t;
        const float mx = means3d[g * 3 + 0];
        const float my = means3d[g * 3 + 1];
        const float mz = means3d[g * 3 + 2];
        s_dep[g] = mx * v2 + my * v6 + mz * v10 + v14;
    }
    __syncthreads();

    // partial rank of gaussian `gid` over j in [q*256, q*256+256), float4 reads
    const float myd = s_dep[gid];
    const float4* s4 = (const float4*)s_dep;
    int rank = 0;
#pragma unroll 8
    for (int j4 = q * (NG / 16); j4 < (q + 1) * (NG / 16); j4++) {
        const float4 d = s4[j4];
        const int j = j4 * 4;
        rank += (d.x < myd || (d.x == myd && j + 0 < gid)) ? 1 : 0;
        rank += (d.y < myd || (d.y == myd && j + 1 < gid)) ? 1 : 0;
        rank += (d.z < myd || (d.z == myd && j + 2 < gid)) ? 1 : 0;
        rank += (d.w < myd || (d.w == myd && j + 3 < gid)) ? 1 : 0;
    }
    s_rank[l][q] = rank;
    __syncthreads();

    if (t < 64) {
        rank = s_rank[l][0] + s_rank[l][1] + s_rank[l][2] + s_rank[l][3];

        float V[16], P[16];
#pragma unroll
        for (int j = 0; j < 16; j++) { V[j] = viewm[j]; P[j] = projm[j]; }

        const float mx = means3d[gid * 3 + 0];
        const float my = means3d[gid * 3 + 1];
        const float mz = means3d[gid * 3 + 2];

        const float q0 = mx * V[0] + my * V[4] + mz * V[8]  + V[12];
        const float q1 = mx * V[1] + my * V[5] + mz * V[9]  + V[13];
        const float q2 = mx * V[2] + my * V[6] + mz * V[10] + V[14];
        const float q3 = mx * V[3] + my * V[7] + mz * V[11] + V[15];
        const float h0 = q0 * P[0] + q1 * P[4] + q2 * P[8]  + q3 * P[12];
        const float h1 = q0 * P[1] + q1 * P[5] + q2 * P[9]  + q3 * P[13];
        const float h3 = q0 * P[3] + q1 * P[7] + q2 * P[11] + q3 * P[15];

        const float inv_w = 1.0f / (h3 + 1e-6f);
        const float m2x = ((h0 * inv_w + 1.0f) * (float)WW - 1.0f) * 0.5f;
        const float m2y = ((h1 * inv_w + 1.0f) * (float)HH - 1.0f) * 0.5f;

        const float s2 = scale3d[gid] * FOCAL_F / q2;
        const float radii = s2 * RADII_MULT_F;
        const float kexp = -0.72134752044448170f / (s2 * s2);  // -0.5*log2(e)/s2sq

        const float rminx = fminf(fmaxf(m2x - radii, 0.0f), (float)(WW - 1));
        const float rminy = fminf(fmaxf(m2y - radii, 0.0f), (float)(HH - 1));
        const float rmaxx = fminf(fmaxf(m2x + radii, 0.0f), (float)(WW - 1));
        const float rmaxy = fminf(fmaxf(m2y + radii, 0.0f), (float)(HH - 1));

        float4* wsv = (float4*)ws;
        wsv[rank]          = make_float4(rminx, rmaxx, rminy, rmaxy);
        wsv[NG + rank]     = make_float4(m2x, m2y, kexp, opacity[gid]);
        wsv[2 * NG + rank] = make_float4(features[gid * 3 + 0],
                                         features[gid * 3 + 1],
                                         features[gid * 3 + 2], q2);
    }
}

// 256 blocks = 16 tiles x 16 row-groups; each block = 4 waves = 4 pixel rows.
// Wave w compacts gaussians [w*256,(w+1)*256) into LDS segment w (order across
// segments == depth order), then blends its own row over all 4 segments.
__global__ __launch_bounds__(256) void render_kernel(
    const float* __restrict__ ws, float* __restrict__ out)
{
    __shared__ float4 s_list[4 * SEG][2];   // (attrA, attrB) per entry, 32 KB
    __shared__ int s_cnt[4];

    const int blk  = blockIdx.x;            // 256 blocks
    const int tile = blk >> 4;              // 16 tiles
    const int rg   = blk & 15;              // row-group within tile (4 rows)
    const int u0 = (tile & (WT - 1)) * TILE_PX;
    const int v0 = (tile / WT) * TILE_PX;
    const int t = threadIdx.x;
    const int l = t & 63;
    const int w = t >> 6;

    const int pxi = u0 + l;
    const int pyi = v0 + rg * 4 + w;
    const float px = (float)pxi;
    const float py = (float)pyi;
    const float u0f  = (float)u0;
    const float u1f  = (float)(u0 + TILE_PX - 1);
    const float py0f = (float)(v0 + rg * 4);
    const float py3f = py0f + 3.0f;

    const float4* rect4 = (const float4*)ws;
    const float4* attrA = rect4 + NG;
    const float4* attrB = rect4 + 2 * NG;

    // ---- hoist ALL global loads (independent, issue back-to-back) ----
    float4 rc[4], aA[4], aB[4];
#pragma unroll
    for (int it = 0; it < 4; it++) {
        const int g = (w << 8) + (it << 6) + l;
        rc[it] = rect4[g];
        aA[it] = attrA[g];
        aB[it] = attrB[g];
    }

    // ---- order-preserving ballot compaction, one quarter per wave ----
    int cnt = 0;
#pragma unroll
    for (int it = 0; it < 4; it++) {
        const bool pass = (fminf(rc[it].y, u1f) > fmaxf(rc[it].x, u0f)) &&
                          (rc[it].z <= py3f) && (rc[it].w >= py0f);
        const unsigned long long m = __ballot(pass);
        if (pass) {
            const int off = (w << 8) + cnt + __popcll(m & ((1ull << l) - 1ull));
            s_list[off][0] = aA[it];
            s_list[off][1] = aB[it];
        }
        cnt += __popcll(m);
    }
    if (l == 0) s_cnt[w] = cnt;
    __syncthreads();

    // ---- front-to-back blend over the 4 ordered segments, 8-wide chunks ----
    float T = 1.0f, cr = 0.0f, cg = 0.0f, cb = 0.0f, dsum = 0.0f, accsum = 0.0f;
    for (int s = 0; s < 4; s++) {
        const int n = s_cnt[s];
        const int base = s << 8;
        for (int eb = 0; eb < n; eb += 8) {
            float4 A[8], B[8];
            float al[8];
            // batch the broadcast LDS reads (one latency, amortized over 8)
#pragma unroll
            for (int i = 0; i < 8; i++) {
                if (eb + i < n) {
                    A[i] = s_list[base + eb + i][0];
                    B[i] = s_list[base + eb + i][1];
                }
            }
            // independent alpha computes (no T dependency)
#pragma unroll
            for (int i = 0; i < 8; i++) {
                if (eb + i < n) {
                    const float dx = px - A[i].x;
                    const float dy = py - A[i].y;
                    const float d2 = fmaf(dx, dx, dy * dy);
                    al[i] = fminf(exp2f(d2 * A[i].z) * A[i].w, 0.99f);
                }
            }
            // short serial T-chain
#pragma unroll
            for (int i = 0; i < 8; i++) {
                if (eb + i < n) {
                    const float wgt = al[i] * T;
                    cr   = fmaf(wgt, B[i].x, cr);
                    cg   = fmaf(wgt, B[i].y, cg);
                    cb   = fmaf(wgt, B[i].z, cb);
                    dsum = fmaf(wgt, B[i].w, dsum);
                    accsum += wgt;
                    T = fmaf(-al[i], T, T);      // T *= (1 - alpha)
                }
            }
        }
    }

    const float bg = 1.0f - accsum;
    cr = fminf(fmaxf(cr + bg, 0.0f), 1.0f);
    cg = fminf(fmaxf(cg + bg, 0.0f), 1.0f);
    cb = fminf(fmaxf(cb + bg, 0.0f), 1.0f);

    const int pix = pyi * WW + pxi;
    out[pix * 3 + 0] = cr;
    out[pix * 3 + 1] = cg;
    out[pix * 3 + 2] = cb;
    out[WW * HH * 3 + pix] = dsum;
    out[WW * HH * 4 + pix] = accsum;
}

extern "C" void kernel_launch(void* const* d_in, const int* in_sizes, int n_in,
                              void* d_out, int out_size, void* d_ws, size_t ws_size,
                              hipStream_t stream) {
    const float* means3d  = (const float*)d_in[0];
    const float* opacity  = (const float*)d_in[1];
    const float* scale3d  = (const float*)d_in[2];
    const float* features = (const float*)d_in[3];
    const float* viewm    = (const float*)d_in[4];
    const float* projm    = (const float*)d_in[5];
    float* ws  = (float*)d_ws;
    float* out = (float*)d_out;

    prep_rank_kernel<<<16, 256, 0, stream>>>(means3d, opacity, scale3d, features,
                                             viewm, projm, ws);
    render_kernel<<<256, 256, 0, stream>>>(ws, out);
}

// Round 3
// 69.631 us; speedup vs baseline: 1.1389x; 1.1389x over previous
//
#include <hip/hip_runtime.h>
#include <math.h>

#define NG 1024
#define HH 256
#define WW 256
#define TILE_PX 64
#define WT 4
#define FOCAL_F 256.0f      // W / (2 * TAN_FOV)
#define RADII_MULT_F 5.0f

// Single fused kernel: 256 blocks = 16 tiles x 16 row-groups, 4 waves/block.
// Each block redundantly projects all 1024 gaussians (4 per thread), compacts
// the ones overlapping its 64x4 pixel window, sorts the survivors by depth
// (stable: key = monotone(depth_bits) << 32 | gid), then blends front-to-back.
// No workspace, no second kernel, no global sort.
__global__ __launch_bounds__(256) void fused_render_kernel(
    const float* __restrict__ means3d, const float* __restrict__ opacity,
    const float* __restrict__ scale3d, const float* __restrict__ features,
    const float* __restrict__ viewm, const float* __restrict__ projm,
    float* __restrict__ out)
{
    __shared__ float4 s_sorted[NG][2];            // 32 KB: (attrA, attrB) at ranked pos
    __shared__ unsigned long long s_key[NG];      // 8 KB: compacted keys, 4 segments
    __shared__ int s_cnt[4];

    const int blk  = blockIdx.x;                  // 256 blocks
    const int tile = blk >> 4;                    // 16 tiles
    const int rg   = blk & 15;                    // row-group (4 rows) within tile
    const int u0 = (tile & (WT - 1)) * TILE_PX;
    const int v0 = (tile / WT) * TILE_PX;
    const int t = threadIdx.x;
    const int l = t & 63;
    const int w = t >> 6;

    const int pxi = u0 + l;
    const int pyi = v0 + rg * 4 + w;
    const float px = (float)pxi;
    const float py = (float)pyi;
    const float u0f  = (float)u0;
    const float u1f  = (float)(u0 + TILE_PX - 1);
    const float py0f = (float)(v0 + rg * 4);
    const float py3f = py0f + 3.0f;

    // matrices (broadcast scalar loads)
    float V[16], P[16];
#pragma unroll
    for (int j = 0; j < 16; j++) { V[j] = viewm[j]; P[j] = projm[j]; }

    // ---- raw inputs for my 4 gaussians (g = k*256 + t), coalesced ----
    float mx[4], my[4], mz[4], sc[4], op[4], fr[4], fg[4], fb[4];
#pragma unroll
    for (int k = 0; k < 4; k++) {
        const int g = (k << 8) + t;
        mx[k] = means3d[g * 3 + 0];
        my[k] = means3d[g * 3 + 1];
        mz[k] = means3d[g * 3 + 2];
        sc[k] = scale3d[g];
        op[k] = opacity[g];
        fr[k] = features[g * 3 + 0];
        fg[k] = features[g * 3 + 1];
        fb[k] = features[g * 3 + 2];
    }

    // ---- project + window-test + per-wave ballot compaction (keys to LDS) ----
    float4 eA[4], eB[4];
    unsigned long long ekey[4];
    int epos[4];
    int cnt = 0;
#pragma unroll
    for (int k = 0; k < 4; k++) {
        const int g = (k << 8) + t;
        const float q0 = mx[k] * V[0] + my[k] * V[4] + mz[k] * V[8]  + V[12];
        const float q1 = mx[k] * V[1] + my[k] * V[5] + mz[k] * V[9]  + V[13];
        const float q2 = mx[k] * V[2] + my[k] * V[6] + mz[k] * V[10] + V[14];
        const float q3 = mx[k] * V[3] + my[k] * V[7] + mz[k] * V[11] + V[15];
        const float h0 = q0 * P[0] + q1 * P[4] + q2 * P[8]  + q3 * P[12];
        const float h1 = q0 * P[1] + q1 * P[5] + q2 * P[9]  + q3 * P[13];
        const float h3 = q0 * P[3] + q1 * P[7] + q2 * P[11] + q3 * P[15];

        const float inv_w = 1.0f / (h3 + 1e-6f);
        const float m2x = ((h0 * inv_w + 1.0f) * (float)WW - 1.0f) * 0.5f;
        const float m2y = ((h1 * inv_w + 1.0f) * (float)HH - 1.0f) * 0.5f;

        const float s2 = sc[k] * FOCAL_F / q2;
        const float radii = s2 * RADII_MULT_F;
        const float kexp = -0.72134752044448170f / (s2 * s2);  // -0.5*log2(e)/s2sq

        const float rminx = fminf(fmaxf(m2x - radii, 0.0f), (float)(WW - 1));
        const float rminy = fminf(fmaxf(m2y - radii, 0.0f), (float)(HH - 1));
        const float rmaxx = fminf(fmaxf(m2x + radii, 0.0f), (float)(WW - 1));
        const float rmaxy = fminf(fmaxf(m2y + radii, 0.0f), (float)(HH - 1));

        const bool pass = (fminf(rmaxx, u1f) > fmaxf(rminx, u0f)) &&
                          (rminy <= py3f) && (rmaxy >= py0f);
        const unsigned long long m = __ballot(pass);
        epos[k] = -1;
        if (pass) {
            const int off = (w << 8) + cnt + __popcll(m & ((1ull << l) - 1ull));
            epos[k] = off;
            eA[k] = make_float4(m2x, m2y, kexp, op[k]);
            eB[k] = make_float4(fr[k], fg[k], fb[k], q2);
            // monotone float->uint map (handles any sign), gid in low bits = stable
            unsigned int ub = __float_as_uint(q2);
            ub = (ub & 0x80000000u) ? ~ub : (ub | 0x80000000u);
            ekey[k] = ((unsigned long long)ub << 32) | (unsigned int)g;
            s_key[off] = ekey[k];
        }
        cnt += __popcll(m);
    }
    if (l == 0) s_cnt[w] = cnt;
    __syncthreads();

    const int c0 = s_cnt[0], c1 = s_cnt[1], c2 = s_cnt[2], c3 = s_cnt[3];
    const int n = c0 + c1 + c2 + c3;

    // ---- rank my entries: count keys strictly smaller (broadcast scan) ----
    int rk[4] = {0, 0, 0, 0};
#pragma unroll
    for (int s = 0; s < 4; s++) {
        const int cn = (s == 0) ? c0 : (s == 1) ? c1 : (s == 2) ? c2 : c3;
        const int base = s << 8;
        for (int j = 0; j < cn; j++) {
            const unsigned long long k2 = s_key[base + j];
#pragma unroll
            for (int k = 0; k < 4; k++)
                if (epos[k] >= 0 && k2 < ekey[k]) rk[k]++;
        }
    }

    // ---- scatter register-held attrs straight to ranked slots ----
#pragma unroll
    for (int k = 0; k < 4; k++) {
        if (epos[k] >= 0) {
            s_sorted[rk[k]][0] = eA[k];
            s_sorted[rk[k]][1] = eB[k];
        }
    }
    __syncthreads();

    // ---- front-to-back blend (broadcast LDS reads) ----
    float T = 1.0f, cr = 0.0f, cg = 0.0f, cb = 0.0f, dsum = 0.0f, accsum = 0.0f;
    for (int e = 0; e < n; e++) {
        const float4 a = s_sorted[e][0];
        const float4 b = s_sorted[e][1];
        const float dx = px - a.x;
        const float dy = py - a.y;
        const float d2 = fmaf(dx, dx, dy * dy);
        const float gw = exp2f(d2 * a.z);
        const float alpha = fminf(gw * a.w, 0.99f);
        const float wgt = alpha * T;
        cr   = fmaf(wgt, b.x, cr);
        cg   = fmaf(wgt, b.y, cg);
        cb   = fmaf(wgt, b.z, cb);
        dsum = fmaf(wgt, b.w, dsum);
        accsum += wgt;
        T = fmaf(-alpha, T, T);              // T *= (1 - alpha)
    }

    const float bg = 1.0f - accsum;
    cr = fminf(fmaxf(cr + bg, 0.0f), 1.0f);
    cg = fminf(fmaxf(cg + bg, 0.0f), 1.0f);
    cb = fminf(fmaxf(cb + bg, 0.0f), 1.0f);

    const int pix = pyi * WW + pxi;
    out[pix * 3 + 0] = cr;
    out[pix * 3 + 1] = cg;
    out[pix * 3 + 2] = cb;
    out[WW * HH * 3 + pix] = dsum;
    out[WW * HH * 4 + pix] = accsum;
}

extern "C" void kernel_launch(void* const* d_in, const int* in_sizes, int n_in,
                              void* d_out, int out_size, void* d_ws, size_t ws_size,
                              hipStream_t stream) {
    const float* means3d  = (const float*)d_in[0];
    const float* opacity  = (const float*)d_in[1];
    const float* scale3d  = (const float*)d_in[2];
    const float* features = (const float*)d_in[3];
    const float* viewm    = (const float*)d_in[4];
    const float* projm    = (const float*)d_in[5];
    float* out = (float*)d_out;

    fused_render_kernel<<<256, 256, 0, stream>>>(means3d, opacity, scale3d,
                                                 features, viewm, projm, out);
}